// Round 10
// baseline (256.939 us; speedup 1.0000x reference)
//
#include <hip/hip_runtime.h>
#include <stdint.h>

#define B_   64
#define N_   4096
#define H_   128
#define S_   7
#define D_   32
#define NCH_ 8                        // attn chunks per batch (512 j per block)
#define SCALE_ 0.17677669529663687f   // 32^-0.5
#define EPS_   1e-8f
#define LNEPS_ 1e-5f
#define SLOTSZ_ 14336                 // 64*224 floats per iteration buffer
#define RSSZ_   448                   // 64*7 floats per iteration buffer

typedef __bf16 bf16x8 __attribute__((ext_vector_type(8)));
typedef float  floatx4 __attribute__((ext_vector_type(4)));

__device__ __forceinline__ uint32_t cvt2(float a, float b){
  union { __bf16 h[2]; uint32_t u; } r;
  r.h[0] = (__bf16)a; r.h[1] = (__bf16)b;
  return r.u;
}
__device__ __forceinline__ float bfLO(uint32_t u){ union{uint32_t i; float f;} x; x.i = u << 16;         return x.f; }
__device__ __forceinline__ float bfHI(uint32_t u){ union{uint32_t i; float f;} x; x.i = u & 0xffff0000u; return x.f; }
__device__ __forceinline__ void up8(uint4 u, float* o){
  o[0]=bfLO(u.x); o[1]=bfHI(u.x); o[2]=bfLO(u.y); o[3]=bfHI(u.y);
  o[4]=bfLO(u.z); o[5]=bfHI(u.z); o[6]=bfLO(u.w); o[7]=bfHI(u.w);
}

// ---------------------------------------------------------------- init: W-fragments (g-folded, bf16) + c1/c2 + A0 prep + zero iter buffers
// grid 69: blocks 0-3 frags, block 4 c1/c2, blocks 5-68 per-batch A0.
__global__ __launch_bounds__(256) void init_w(const float* __restrict__ Wk, const float* __restrict__ Wv,
                                              const float* __restrict__ g,  const float* __restrict__ bta,
                                              uint16_t* __restrict__ fragbuf,
                                              float* __restrict__ c1arr, float* __restrict__ c2arr,
                                              const float* __restrict__ sini,
                                              float* __restrict__ slotsbuf, float* __restrict__ qbuf,
                                              float* __restrict__ updbuf, float* __restrict__ rowsumbuf,
                                              const float* __restrict__ Wq,
                                              const float* __restrict__ lnsg, const float* __restrict__ lnsb){
  int t = threadIdx.x;
  if (blockIdx.x < 4){
    int tid = blockIdx.x * 256 + t;
    int nt = tid >> 8, kc = (tid >> 6) & 3, l = tid & 63;
    int col = (nt & 1) * 16 + (l & 15);
    int dbase = kc * 32 + (l >> 4) * 8;
    const float* wr = (nt < 2 ? Wk : Wv) + col * 128 + dbase;
    const float* gr = g + dbase;
    uint32_t u[4];
    #pragma unroll
    for (int j = 0; j < 4; ++j)
      u[j] = cvt2(wr[2*j] * gr[2*j], wr[2*j+1] * gr[2*j+1]);
    *reinterpret_cast<uint4*>(fragbuf + (size_t)tid * 8) = make_uint4(u[0], u[1], u[2], u[3]);
  } else if (blockIdx.x == 4){
    if (t < 128){
      int which = t >> 5, col = t & 31;                 // 0:c1K 1:c2K 2:c1V 3:c2V
      const float* Wb  = (which & 2) ? Wv : Wk;
      const float* vec = (which & 1) ? bta : g;
      float a = 0.f;
      for (int d = 0; d < 128; ++d) a += vec[d] * Wb[col * 128 + d];
      float* dst = (which & 1) ? c2arr : c1arr;
      dst[(which >> 1) * 32 + col] = a;
    }
  } else {
    int b = blockIdx.x - 5;
    int i = t >> 5, c = t & 31;
    __shared__ float sNew[224], sT[224];
    if (t < 224){
      float s = sini[b * 224 + t];
      slotsbuf[b * 224 + t] = s;                        // S_0
      sNew[t] = s;
      #pragma unroll
      for (int m4 = 0; m4 < 4; ++m4) updbuf[m4 * SLOTSZ_ + b * 224 + t] = 0.f;
    }
    if (t < 7){
      #pragma unroll
      for (int m4 = 0; m4 < 4; ++m4) rowsumbuf[m4 * RSSZ_ + b * S_ + t] = 0.f;
    }
    __syncthreads();
    if (t < 224){                                       // LN_s
      float mu = 0.f, sq = 0.f;
      #pragma unroll
      for (int d = 0; d < 32; ++d){ float v = sNew[i * 32 + d]; mu += v; sq += v * v; }
      mu *= (1.f / 32.f);
      float var = sq * (1.f / 32.f) - mu * mu;
      float rstd = rsqrtf(var + LNEPS_);
      sT[t] = (sNew[t] - mu) * rstd * lnsg[c] + lnsb[c];
    }
    __syncthreads();
    if (t < 224){                                       // q0
      float a = 0.f;
      #pragma unroll
      for (int d = 0; d < 32; ++d) a += sT[i * 32 + d] * Wq[c * 32 + d];
      qbuf[b * 224 + t] = a;
    }
  }
}

// ---------------------------------------------------------------- LN(inputs) -> k,v via MFMA (LN folded), bf16 out
// 64 rows per block, 256 threads (4 waves, each 32 rows x 32 cols). Grid 4096.
__global__ __launch_bounds__(256) void ln_kv(const float* __restrict__ x,
                                             const uint16_t* __restrict__ fragbuf,
                                             const float* __restrict__ c1arr, const float* __restrict__ c2arr,
                                             uint16_t* __restrict__ kb, uint16_t* __restrict__ vb){
  __shared__ union {
    uint16_t atile[64 * 136];          // bf16 raw-x tile, row stride 136 (272B)
    float    rep[4352];                // repack: k[64][34], v at +2176
  } sh;
  __shared__ float2 stats[64 * 8];     // [row][grp] 4-lane partials
  __shared__ float2 rowstat[64];       // (rstd, -mu*rstd)
  int t = threadIdx.x;
  int l = t & 63, w = t >> 6;
  int half = w >> 1;                   // 0: k, 1: v
  int r0 = (w & 1) * 32;
  size_t rowbase = (size_t)blockIdx.x * 64;

  // ---- B-frags (2 nt halves for this wave) + epilogue constants
  bf16x8 bfr[2][4];
  float c1c[2], c2c[2];
  #pragma unroll
  for (int n2 = 0; n2 < 2; ++n2){
    #pragma unroll
    for (int kc = 0; kc < 4; ++kc)
      bfr[n2][kc] = *reinterpret_cast<const bf16x8*>(fragbuf + ((((half*2+n2) * 4 + kc) * 64 + l) * 8));
    int colk = n2 * 16 + (l & 15);
    c1c[n2] = c1arr[half * 32 + colk];
    c2c[n2] = c2arr[half * 32 + colk];
  }

  // ---- pass1: load raw x, cast bf16 -> LDS, 4-lane pre-reduced stats -> LDS
  const float4* xp = reinterpret_cast<const float4*>(x + rowbase * H_);
  #pragma unroll
  for (int k = 0; k < 8; ++k){
    float4 v = xp[k * 256 + t];        // coalesced 1KB per wave
    int row = 8 * k + (t >> 5);
    uint32_t lo = cvt2(v.x, v.y);
    uint32_t hi = cvt2(v.z, v.w);
    *reinterpret_cast<uint2*>(&sh.atile[row * 136 + (t & 31) * 4]) = make_uint2(lo, hi);
    float s  = v.x + v.y + v.z + v.w;
    float s2 = v.x*v.x + v.y*v.y + v.z*v.z + v.w*v.w;
    s  += __shfl_xor(s, 1);  s2 += __shfl_xor(s2, 1);
    s  += __shfl_xor(s, 2);  s2 += __shfl_xor(s2, 2);
    if ((t & 3) == 0) stats[row * 8 + ((t & 31) >> 2)] = make_float2(s, s2);
  }
  __syncthreads();

  // ---- stats: 8 LDS reads per row
  if (t < 64){
    float s = 0.f, s2 = 0.f;
    #pragma unroll
    for (int jx = 0; jx < 8; ++jx){
      float2 p = stats[t * 8 + jx];
      s += p.x; s2 += p.y;
    }
    float mean = s * (1.f / 128.f);
    float var  = s2 * (1.f / 128.f) - mean * mean;
    float rstd = rsqrtf(var + LNEPS_);
    rowstat[t] = make_float2(rstd, -mean * rstd);
  }
  __syncthreads();

  // ---- MFMA: wave w -> rows r0..r0+31, 32 cols of (half? v : k)
  floatx4 acc[2][2] = {{{0,0,0,0},{0,0,0,0}},{{0,0,0,0},{0,0,0,0}}};
  #pragma unroll
  for (int kc = 0; kc < 4; ++kc){
    bf16x8 afr0 = *reinterpret_cast<const bf16x8*>(
        &sh.atile[(r0 +      (l & 15)) * 136 + kc * 32 + (l >> 4) * 8]);
    bf16x8 afr1 = *reinterpret_cast<const bf16x8*>(
        &sh.atile[(r0 + 16 + (l & 15)) * 136 + kc * 32 + (l >> 4) * 8]);
    #pragma unroll
    for (int n2 = 0; n2 < 2; ++n2){
      acc[0][n2] = __builtin_amdgcn_mfma_f32_16x16x32_bf16(afr0, bfr[n2][kc], acc[0][n2], 0, 0, 0);
      acc[1][n2] = __builtin_amdgcn_mfma_f32_16x16x32_bf16(afr1, bfr[n2][kc], acc[1][n2], 0, 0, 0);
    }
  }
  __syncthreads();                     // atile dead; rep aliases it

  // ---- epilogue into LDS repack
  int base = half * 2176;
  #pragma unroll
  for (int rt = 0; rt < 2; ++rt){
    #pragma unroll
    for (int j = 0; j < 4; ++j){
      int rloc = r0 + rt * 16 + (l >> 4) * 4 + j;
      float2 ab = rowstat[rloc];
      #pragma unroll
      for (int n2 = 0; n2 < 2; ++n2)
        sh.rep[base + rloc * 34 + n2 * 16 + (l & 15)] =
            fmaf(ab.x, acc[rt][n2][j], fmaf(ab.y, c1c[n2], c2c[n2]));
    }
  }
  __syncthreads();

  // ---- pack bf16, coalesced uint4 stores (256 uint4 per buffer; 4 uint4 per 32-col row)
  uint4* kout4 = reinterpret_cast<uint4*>(kb + rowbase * 32);
  uint4* vout4 = reinterpret_cast<uint4*>(vb + rowbase * 32);
  {
    int row = t >> 2, w8 = t & 3;                // w8*8 in {0,8,16,24}, +7 < 32 valid cols
    const float* sk = &sh.rep[row * 34 + w8 * 8];
    const float* sv = &sh.rep[2176 + row * 34 + w8 * 8];
    kout4[t] = make_uint4(cvt2(sk[0],sk[1]), cvt2(sk[2],sk[3]), cvt2(sk[4],sk[5]), cvt2(sk[6],sk[7]));
    vout4[t] = make_uint4(cvt2(sv[0],sv[1]), cvt2(sv[2],sv[3]), cvt2(sv[4],sv[5]), cvt2(sv[6],sv[7]));
  }
}

// ---------------------------------------------------------------- attention iteration with in-block slot-update prologue
// grid (NCH_=8, 64). For m>=1 every block recomputes slots S_m from iter-(m-1)
// buffers (kernel-boundary coherence, no fences); chunk 0 persists S_m.
__global__ __launch_bounds__(256) void attn_iter(
    const uint16_t* __restrict__ kb, const uint16_t* __restrict__ vb,
    const float* __restrict__ qbuf,
    float* __restrict__ updbuf, float* __restrict__ rowsumbuf,
    float* __restrict__ slotsbuf, float* __restrict__ aubuf,
    const float* __restrict__ gwi, const float* __restrict__ gwh,
    const float* __restrict__ gbi, const float* __restrict__ gbh,
    const float* __restrict__ lnmg, const float* __restrict__ lnmb,
    const float* __restrict__ w1, const float* __restrict__ b1,
    const float* __restrict__ w2, const float* __restrict__ b2,
    const float* __restrict__ Wq, const float* __restrict__ lnsg, const float* __restrict__ lnsb,
    int m)
{
  __shared__ float au[S_ * 257];       // [7][257] padded
  __shared__ union {
    float vtile[256 * 32];             // [256][32] f32, XOR-swizzled float4 blocks
    struct { float sPrev[224], sU[224], sNew[224], sT[224], hM[896]; } tl;
  } shv;
  __shared__ float qtile[224];         // survives vtile overwrites
  int b = blockIdx.y, chunk = blockIdx.x, t = threadIdx.x;
  int i7 = t >> 5, c = t & 31;

  // ================ prologue: slot update #m -> q_m ================
  if (m == 0){
    if (t < 224) qtile[t] = qbuf[b * 224 + t];
  } else {
    const float* sprev = slotsbuf + (size_t)(m-1) * SLOTSZ_ + b * 224;
    const float* updp  = updbuf   + (size_t)(m-1) * SLOTSZ_ + b * 224;
    const float* rsp   = rowsumbuf + (m-1) * RSSZ_ + b * S_;
    float snew = 0.f;
    if (t < 224){
      shv.tl.sPrev[t] = sprev[t];
      shv.tl.sU[t]    = updp[t] / rsp[i7];
    }
    __syncthreads();
    if (t < 224){                                       // GRU
      float gi[3], gh[3];
      #pragma unroll
      for (int x3 = 0; x3 < 3; ++x3){
        int gg = x3 * 32 + c;
        float ai = gbi[gg], ah = gbh[gg];
        #pragma unroll
        for (int d = 0; d < 32; ++d){
          ai += shv.tl.sU[i7 * 32 + d]    * gwi[gg * 32 + d];
          ah += shv.tl.sPrev[i7 * 32 + d] * gwh[gg * 32 + d];
        }
        gi[x3] = ai; gh[x3] = ah;
      }
      float r = 1.f / (1.f + __expf(-(gi[0] + gh[0])));
      float z = 1.f / (1.f + __expf(-(gi[1] + gh[1])));
      float n = tanhf(gi[2] + r * gh[2]);
      snew = (1.f - z) * n + z * shv.tl.sPrev[t];
      shv.tl.sNew[t] = snew;
    }
    __syncthreads();
    if (t < 224){                                       // LN_m
      float mu = 0.f, sq = 0.f;
      #pragma unroll
      for (int d = 0; d < 32; ++d){ float v = shv.tl.sNew[i7 * 32 + d]; mu += v; sq += v * v; }
      mu *= (1.f / 32.f);
      float var = sq * (1.f / 32.f) - mu * mu;
      float rstd = rsqrtf(var + LNEPS_);
      shv.tl.sT[t] = (snew - mu) * rstd * lnmg[c] + lnmb[c];
    }
    __syncthreads();
    if (t < 224){                                       // MLP layer 1
      #pragma unroll
      for (int kk = 0; kk < 4; ++kk){
        int hc = c + kk * 32;
        float a = b1[hc];
        #pragma unroll
        for (int d = 0; d < 32; ++d) a += shv.tl.sT[i7 * 32 + d] * w1[hc * 32 + d];
        shv.tl.hM[i7 * 128 + hc] = fmaxf(a, 0.f);
      }
    }
    __syncthreads();
    if (t < 224){                                       // MLP layer 2 + residual -> S_m
      float a0 = 0.f, a1 = 0.f, a2 = 0.f, a3 = 0.f;
      for (int hh = 0; hh < 128; hh += 4){
        a0 += shv.tl.hM[i7 * 128 + hh    ] * w2[c * 128 + hh    ];
        a1 += shv.tl.hM[i7 * 128 + hh + 1] * w2[c * 128 + hh + 1];
        a2 += shv.tl.hM[i7 * 128 + hh + 2] * w2[c * 128 + hh + 2];
        a3 += shv.tl.hM[i7 * 128 + hh + 3] * w2[c * 128 + hh + 3];
      }
      snew = snew + b2[c] + ((a0 + a1) + (a2 + a3));
      shv.tl.sNew[t] = snew;
      if (chunk == 0) slotsbuf[(size_t)m * SLOTSZ_ + b * 224 + t] = snew;   // persist S_m
    }
    __syncthreads();
    if (t < 224){                                       // LN_s
      float mu = 0.f, sq = 0.f;
      #pragma unroll
      for (int d = 0; d < 32; ++d){ float v = shv.tl.sNew[i7 * 32 + d]; mu += v; sq += v * v; }
      mu *= (1.f / 32.f);
      float var = sq * (1.f / 32.f) - mu * mu;
      float rstd = rsqrtf(var + LNEPS_);
      shv.tl.sT[t] = (shv.tl.sNew[t] - mu) * rstd * lnsg[c] + lnsb[c];
    }
    __syncthreads();
    if (t < 224){                                       // q_m
      float a = 0.f;
      #pragma unroll
      for (int d = 0; d < 32; ++d) a += shv.tl.sT[i7 * 32 + d] * Wq[c * 32 + d];
      qtile[t] = a;
    }
  }
  __syncthreads();

  // ================ attention over 512 j (2 tiles) ================
  int rem = t % 56, prt = t / 56;      // valid for t<224
  int pi = rem >> 3, pc4 = rem & 7;

  float rs[7];
  #pragma unroll
  for (int i = 0; i < 7; ++i) rs[i] = 0.f;
  float ux = 0.f, uy = 0.f, uz = 0.f, uw = 0.f;
  float* updp_w = updbuf + (size_t)m * SLOTSZ_;
  float* rsp_w  = rowsumbuf + m * RSSZ_;

  for (int tile = 0; tile < 2; ++tile){
    int j = chunk * 512 + tile * 256 + t;
    const uint4* kr = reinterpret_cast<const uint4*>(kb + ((size_t)b * N_ + j) * 32);
    float kf[32];
    #pragma unroll
    for (int p = 0; p < 4; ++p) up8(kr[p], kf + p * 8);

    float dv[7];
    #pragma unroll
    for (int i = 0; i < 7; ++i){
      float a = 0.f;
      #pragma unroll
      for (int c4 = 0; c4 < 8; ++c4){
        float4 q4 = *reinterpret_cast<const float4*>(&qtile[i * 32 + c4 * 4]);  // LDS broadcast
        a += q4.x * kf[c4*4] + q4.y * kf[c4*4+1] + q4.z * kf[c4*4+2] + q4.w * kf[c4*4+3];
      }
      dv[i] = a * SCALE_;
    }
    float mx = dv[0];
    #pragma unroll
    for (int i = 1; i < 7; ++i) mx = fmaxf(mx, dv[i]);
    float p[7]; float sum = 0.f;
    #pragma unroll
    for (int i = 0; i < 7; ++i){ p[i] = __expf(dv[i] - mx); sum += p[i]; }
    float inv = 1.f / sum;
    #pragma unroll
    for (int i = 0; i < 7; ++i){
      p[i] = p[i] * inv + EPS_;
      rs[i] += p[i];
      au[i * 257 + t] = p[i];
    }
    if (m == 3){
      #pragma unroll
      for (int i = 0; i < 7; ++i) aubuf[(size_t)(b * S_ + i) * N_ + j] = p[i];
    }
    // stage v tile (f32, XOR-swizzled 16B blocks)
    const uint4* vr = reinterpret_cast<const uint4*>(vb + ((size_t)b * N_ + j) * 32);
    float vf[32];
    #pragma unroll
    for (int p4 = 0; p4 < 4; ++p4) up8(vr[p4], vf + p4 * 8);
    #pragma unroll
    for (int q4 = 0; q4 < 8; ++q4){
      int blk = q4 ^ (t & 7);
      *reinterpret_cast<float4*>(&shv.vtile[t * 32 + blk * 4]) =
          make_float4(vf[q4*4], vf[q4*4+1], vf[q4*4+2], vf[q4*4+3]);
    }
    __syncthreads();

    if (t < 224){
      const float* aur = au + pi * 257 + prt * 64;
      #pragma unroll 4
      for (int jj0 = 0; jj0 < 64; ++jj0){
        int jj = prt * 64 + jj0;
        float a = aur[jj0];
        int blk = pc4 ^ (jj & 7);
        float4 vv = *reinterpret_cast<const float4*>(&shv.vtile[jj * 32 + blk * 4]);
        ux += a * vv.x; uy += a * vv.y; uz += a * vv.z; uw += a * vv.w;
      }
    }
    __syncthreads();
  }

  // ---- rowsum: barrier-free wave shfl reduce, per-wave lane-0 atomics
  #pragma unroll
  for (int i = 0; i < 7; ++i){
    float v = rs[i];
    v += __shfl_xor(v, 1);  v += __shfl_xor(v, 2);  v += __shfl_xor(v, 4);
    v += __shfl_xor(v, 8);  v += __shfl_xor(v, 16); v += __shfl_xor(v, 32);
    rs[i] = v;
  }
  if ((t & 63) == 0){
    #pragma unroll
    for (int i = 0; i < 7; ++i) atomicAdd(&rsp_w[b * S_ + i], rs[i]);
  }
  if (t < 224){
    float* up = updp_w + (size_t)(b * S_ + pi) * 32 + pc4 * 4;
    atomicAdd(up + 0, ux); atomicAdd(up + 1, uy);
    atomicAdd(up + 2, uz); atomicAdd(up + 3, uw);
  }
}

// ---------------------------------------------------------------- finalize: blocks 0-63 slot update #4 -> out0/out2; blocks 64-511 normalize -> out1
__global__ __launch_bounds__(256) void finalize(
    const float* __restrict__ slotsbuf, const float* __restrict__ updbuf,
    const float* __restrict__ rowsumbuf, const float* __restrict__ aubuf,
    const float* __restrict__ gwi, const float* __restrict__ gwh,
    const float* __restrict__ gbi, const float* __restrict__ gbh,
    const float* __restrict__ lnmg, const float* __restrict__ lnmb,
    const float* __restrict__ w1, const float* __restrict__ b1,
    const float* __restrict__ w2, const float* __restrict__ b2,
    float* __restrict__ out0, float* __restrict__ out1, float* __restrict__ out2)
{
  int t = threadIdx.x;
  if (blockIdx.x >= 64){
    int blk = blockIdx.x - 64;                          // 0..447
    const float* rsp = rowsumbuf + 3 * RSSZ_;
    #pragma unroll
    for (int k2 = 0; k2 < 4; ++k2){
      int idx4 = blk * 1024 + k2 * 256 + t;             // < 458752
      int bi = idx4 >> 10;                              // (b*7+i)
      float inv = 1.f / rsp[bi];
      float4 a = reinterpret_cast<const float4*>(aubuf)[idx4];
      reinterpret_cast<float4*>(out1)[idx4] = make_float4(a.x*inv, a.y*inv, a.z*inv, a.w*inv);
    }
    return;
  }
  int b = blockIdx.x;
  int i7 = t >> 5, c = t & 31;
  __shared__ float sPrev[224], sU[224], sNew[224], sT[224], hM[896];
  const float* sprev = slotsbuf + (size_t)3 * SLOTSZ_ + b * 224;
  const float* updp  = updbuf   + (size_t)3 * SLOTSZ_ + b * 224;
  const float* rsp   = rowsumbuf + 3 * RSSZ_ + b * S_;
  float snew = 0.f;
  if (t < 224){
    sPrev[t] = sprev[t];
    sU[t] = updp[t] / rsp[i7];
  }
  __syncthreads();
  if (t < 224){                                         // GRU
    float gi[3], gh[3];
    #pragma unroll
    for (int x3 = 0; x3 < 3; ++x3){
      int gg = x3 * 32 + c;
      float ai = gbi[gg], ah = gbh[gg];
      #pragma unroll
      for (int d = 0; d < 32; ++d){
        ai += sU[i7 * 32 + d]    * gwi[gg * 32 + d];
        ah += sPrev[i7 * 32 + d] * gwh[gg * 32 + d];
      }
      gi[x3] = ai; gh[x3] = ah;
    }
    float r = 1.f / (1.f + __expf(-(gi[0] + gh[0])));
    float z = 1.f / (1.f + __expf(-(gi[1] + gh[1])));
    float n = tanhf(gi[2] + r * gh[2]);
    snew = (1.f - z) * n + z * sPrev[t];
    sNew[t] = snew;
  }
  __syncthreads();
  if (t < 224){                                         // LN_m
    float mu = 0.f, sq = 0.f;
    #pragma unroll
    for (int d = 0; d < 32; ++d){ float v = sNew[i7 * 32 + d]; mu += v; sq += v * v; }
    mu *= (1.f / 32.f);
    float var = sq * (1.f / 32.f) - mu * mu;
    float rstd = rsqrtf(var + LNEPS_);
    sT[t] = (snew - mu) * rstd * lnmg[c] + lnmb[c];
  }
  __syncthreads();
  if (t < 224){                                         // MLP layer 1
    #pragma unroll
    for (int kk = 0; kk < 4; ++kk){
      int hc = c + kk * 32;
      float a = b1[hc];
      #pragma unroll
      for (int d = 0; d < 32; ++d) a += sT[i7 * 32 + d] * w1[hc * 32 + d];
      hM[i7 * 128 + hc] = fmaxf(a, 0.f);
    }
  }
  __syncthreads();
  if (t < 224){                                         // MLP layer 2 + residual -> final slots
    float a0 = 0.f, a1 = 0.f, a2 = 0.f, a3 = 0.f;
    for (int hh = 0; hh < 128; hh += 4){
      a0 += hM[i7 * 128 + hh    ] * w2[c * 128 + hh    ];
      a1 += hM[i7 * 128 + hh + 1] * w2[c * 128 + hh + 1];
      a2 += hM[i7 * 128 + hh + 2] * w2[c * 128 + hh + 2];
      a3 += hM[i7 * 128 + hh + 3] * w2[c * 128 + hh + 3];
    }
    snew = snew + b2[c] + ((a0 + a1) + (a2 + a3));
    out0[b * 224 + t] = snew;
    out2[b * 224 + t] = snew;
  }
}

// ----------------------------------------------------------------
extern "C" void kernel_launch(void* const* d_in, const int* in_sizes, int n_in,
                              void* d_out, int out_size, void* d_ws, size_t ws_size,
                              hipStream_t stream)
{
  (void)in_sizes; (void)n_in; (void)out_size; (void)ws_size;
  const float* inp   = (const float*)d_in[0];
  const float* sini  = (const float*)d_in[1];
  const float* lng   = (const float*)d_in[2];
  const float* lnb   = (const float*)d_in[3];
  const float* Wk    = (const float*)d_in[4];
  const float* Wv    = (const float*)d_in[5];
  const float* Wq    = (const float*)d_in[6];
  const float* lnsg  = (const float*)d_in[7];
  const float* lnsb  = (const float*)d_in[8];
  const float* gwi   = (const float*)d_in[9];
  const float* gwh   = (const float*)d_in[10];
  const float* gbi   = (const float*)d_in[11];
  const float* gbh   = (const float*)d_in[12];
  const float* lnmg  = (const float*)d_in[13];
  const float* lnmb  = (const float*)d_in[14];
  const float* w1    = (const float*)d_in[15];
  const float* b1    = (const float*)d_in[16];
  const float* w2    = (const float*)d_in[17];
  const float* b2    = (const float*)d_in[18];

  char* w = (char*)d_ws;
  uint16_t* kbuf   = (uint16_t*)w; w += (size_t)B_ * N_ * 32 * 2;
  uint16_t* vbuf   = (uint16_t*)w; w += (size_t)B_ * N_ * 32 * 2;
  float* qbuf      = (float*)w; w += B_ * 224 * 4;
  float* slotsbuf  = (float*)w; w += 4 * SLOTSZ_ * 4;   // S_0..S_3
  float* updbuf    = (float*)w; w += 4 * SLOTSZ_ * 4;   // upd[0..3]
  float* rowsumbuf = (float*)w; w += 4 * RSSZ_ * 4;     // rs[0..3]
  float* aubuf     = (float*)w; w += (size_t)B_ * S_ * N_ * 4;
  uint16_t* fragbuf= (uint16_t*)w; w += 8192 * 2;
  float* c1arr     = (float*)w; w += 64 * 4;
  float* c2arr     = (float*)w; w += 64 * 4;

  float* out0 = (float*)d_out;
  float* out1 = out0 + B_ * S_ * D_;
  float* out2 = out1 + B_ * S_ * N_;

  hipLaunchKernelGGL(init_w, dim3(69), dim3(256), 0, stream,
                     Wk, Wv, lng, lnb, fragbuf, c1arr, c2arr,
                     sini, slotsbuf, qbuf, updbuf, rowsumbuf, Wq, lnsg, lnsb);
  hipLaunchKernelGGL(ln_kv, dim3(4096), dim3(256), 0, stream, inp, fragbuf, c1arr, c2arr, kbuf, vbuf);

  for (int m = 0; m < 4; ++m){
    hipLaunchKernelGGL(attn_iter, dim3(NCH_, 64), dim3(256), 0, stream,
                       kbuf, vbuf, qbuf, updbuf, rowsumbuf, slotsbuf, aubuf,
                       gwi, gwh, gbi, gbh, lnmg, lnmb, w1, b1, w2, b2,
                       Wq, lnsg, lnsb, m);
  }

  hipLaunchKernelGGL(finalize, dim3(512), dim3(256), 0, stream,
                     slotsbuf, updbuf, rowsumbuf, aubuf,
                     gwi, gwh, gbi, gbh, lnmg, lnmb, w1, b1, w2, b2,
                     out0, out1, out2);
}

// Round 11
// 186.295 us; speedup vs baseline: 1.3792x; 1.3792x over previous
//
#include <hip/hip_runtime.h>
#include <stdint.h>

#define B_   64
#define N_   4096
#define H_   128
#define S_   7
#define D_   32
#define SCALE_ 0.17677669529663687f   // 32^-0.5
#define EPS_   1e-8f
#define LNEPS_ 1e-5f

typedef __bf16 bf16x8 __attribute__((ext_vector_type(8)));
typedef float  floatx4 __attribute__((ext_vector_type(4)));

__device__ __forceinline__ uint32_t cvt2(float a, float b){
  union { __bf16 h[2]; uint32_t u; } r;
  r.h[0] = (__bf16)a; r.h[1] = (__bf16)b;
  return r.u;
}
__device__ __forceinline__ float bfLO(uint32_t u){ union{uint32_t i; float f;} x; x.i = u << 16;         return x.f; }
__device__ __forceinline__ float bfHI(uint32_t u){ union{uint32_t i; float f;} x; x.i = u & 0xffff0000u; return x.f; }
__device__ __forceinline__ void up8(uint4 u, float* o){
  o[0]=bfLO(u.x); o[1]=bfHI(u.x); o[2]=bfLO(u.y); o[3]=bfHI(u.y);
  o[4]=bfLO(u.z); o[5]=bfHI(u.z); o[6]=bfLO(u.w); o[7]=bfHI(u.w);
}

// ---------------------------------------------------------------- init: precompute W-fragments (g-folded, bf16) + c1/c2
__global__ __launch_bounds__(256) void init_w(const float* __restrict__ Wk, const float* __restrict__ Wv,
                                              const float* __restrict__ g,  const float* __restrict__ bta,
                                              uint16_t* __restrict__ fragbuf,
                                              float* __restrict__ c1arr, float* __restrict__ c2arr){
  int tid = blockIdx.x * 256 + threadIdx.x;
  if (blockIdx.x < 4){
    int nt = tid >> 8, kc = (tid >> 6) & 3, l = tid & 63;
    int col = (nt & 1) * 16 + (l & 15);
    int dbase = kc * 32 + (l >> 4) * 8;
    const float* wr = (nt < 2 ? Wk : Wv) + col * 128 + dbase;
    const float* gr = g + dbase;
    uint32_t u[4];
    #pragma unroll
    for (int j = 0; j < 4; ++j)
      u[j] = cvt2(wr[2*j] * gr[2*j], wr[2*j+1] * gr[2*j+1]);
    *reinterpret_cast<uint4*>(fragbuf + (size_t)tid * 8) = make_uint4(u[0], u[1], u[2], u[3]);
  } else {
    int t = threadIdx.x;
    if (t < 128){
      int which = t >> 5, col = t & 31;                 // 0:c1K 1:c2K 2:c1V 3:c2V
      const float* Wb  = (which & 2) ? Wv : Wk;
      const float* vec = (which & 1) ? bta : g;
      float a = 0.f;
      for (int d = 0; d < 128; ++d) a += vec[d] * Wb[col * 128 + d];
      float* dst = (which & 1) ? c2arr : c1arr;
      dst[(which >> 1) * 32 + col] = a;
    }
  }
}

// ---------------------------------------------------------------- LN(inputs) -> k,v via MFMA on raw x (LN folded into epilogue)
// 64 rows per block, 256 threads (4 waves). Grid 4096. k/v stored bf16.
__global__ __launch_bounds__(256) void ln_kv(const float* __restrict__ x,
                                             const uint16_t* __restrict__ fragbuf,
                                             const float* __restrict__ c1arr, const float* __restrict__ c2arr,
                                             uint16_t* __restrict__ kb, uint16_t* __restrict__ vb){
  __shared__ union {
    uint16_t atile[64 * 136];          // bf16 raw-x tile, row stride 136 (272B)
    float    rep[4352];                // repack area: k[64][34], v at +2176
  } sh;
  __shared__ float2 stats[32 * 65];    // [c][row] padded partial (s, s2)
  __shared__ float2 rowstat[64];       // (rstd, -mu*rstd)
  int t = threadIdx.x;
  int l = t & 63, w = t >> 6;
  size_t rowbase = (size_t)blockIdx.x * 64;

  // ---- B-frags: precomputed, coalesced dwordx4 loads
  bf16x8 bfr[4][4];                    // [nt][kc]
  #pragma unroll
  for (int nt = 0; nt < 4; ++nt)
    #pragma unroll
    for (int kc = 0; kc < 4; ++kc)
      bfr[nt][kc] = *reinterpret_cast<const bf16x8*>(fragbuf + (((nt * 4 + kc) * 64 + l) * 8));

  // ---- per-thread epilogue constants
  float c1c[4], c2c[4];
  #pragma unroll
  for (int nt = 0; nt < 4; ++nt){
    int colk = (nt & 1) * 16 + (l & 15);
    c1c[nt] = c1arr[(nt >> 1) * 32 + colk];
    c2c[nt] = c2arr[(nt >> 1) * 32 + colk];
  }

  // ---- pass1: load raw x, cast bf16 -> LDS, partial stats -> LDS
  const float4* xp = reinterpret_cast<const float4*>(x + rowbase * H_);
  #pragma unroll
  for (int k = 0; k < 8; ++k){
    float4 v = xp[k * 256 + t];        // coalesced 1KB per wave
    int row = 8 * k + (t >> 5);
    uint32_t lo = cvt2(v.x, v.y);
    uint32_t hi = cvt2(v.z, v.w);
    *reinterpret_cast<uint2*>(&sh.atile[row * 136 + (t & 31) * 4]) = make_uint2(lo, hi);
    float s  = v.x + v.y + v.z + v.w;
    float s2 = v.x*v.x + v.y*v.y + v.z*v.z + v.w*v.w;
    stats[(t & 31) * 65 + row] = make_float2(s, s2);
  }
  __syncthreads();

  // ---- shallow stats reduce: 8 independent LDS reads + 2 shfl levels
  {
    int row = t >> 2, q = t & 3;
    float s = 0.f, s2 = 0.f;
    #pragma unroll
    for (int j = 0; j < 8; ++j){
      float2 p = stats[(q * 8 + j) * 65 + row];
      s += p.x; s2 += p.y;
    }
    s  += __shfl_xor(s, 1);  s2 += __shfl_xor(s2, 1);
    s  += __shfl_xor(s, 2);  s2 += __shfl_xor(s2, 2);
    if (q == 0){
      float mean = s * (1.f / 128.f);
      float var  = s2 * (1.f / 128.f) - mean * mean;
      float rstd = rsqrtf(var + LNEPS_);
      rowstat[row] = make_float2(rstd, -mean * rstd);
    }
  }
  __syncthreads();

  // ---- MFMA: wave w -> rows w*16..w*16+15, all 64 out cols
  floatx4 acc[4] = {{0,0,0,0},{0,0,0,0},{0,0,0,0},{0,0,0,0}};
  #pragma unroll
  for (int kc = 0; kc < 4; ++kc){
    bf16x8 afr = *reinterpret_cast<const bf16x8*>(
        &sh.atile[(w * 16 + (l & 15)) * 136 + kc * 32 + (l >> 4) * 8]);
    #pragma unroll
    for (int nt = 0; nt < 4; ++nt)
      acc[nt] = __builtin_amdgcn_mfma_f32_16x16x32_bf16(afr, bfr[nt][kc], acc[nt], 0, 0, 0);
  }
  __syncthreads();                     // atile dead; rep aliases it

  // ---- epilogue: k = rstd*acc + (-mu*rstd)*c1 + c2 -> LDS repack area
  #pragma unroll
  for (int j = 0; j < 4; ++j){
    int rloc = w * 16 + (l >> 4) * 4 + j;
    float2 ab = rowstat[rloc];
    #pragma unroll
    for (int nt = 0; nt < 4; ++nt){
      int base = (nt < 2) ? 0 : 2176;
      int gc = (nt & 1) * 16 + (l & 15);
      sh.rep[base + rloc * 34 + gc] = fmaf(ab.x, acc[nt][j], fmaf(ab.y, c1c[nt], c2c[nt]));
    }
  }
  __syncthreads();

  // ---- pack bf16 pairs, coalesced uint32 stores
  uint32_t* kout = reinterpret_cast<uint32_t*>(kb + rowbase * 32);
  uint32_t* vout = reinterpret_cast<uint32_t*>(vb + rowbase * 32);
  #pragma unroll
  for (int it = 0; it < 4; ++it){
    int lin = it * 256 + t;
    int row = lin >> 4, wd = (lin & 15) * 2;
    kout[lin] = cvt2(sh.rep[row * 34 + wd],        sh.rep[row * 34 + wd + 1]);
    vout[lin] = cvt2(sh.rep[2176 + row * 34 + wd], sh.rep[2176 + row * 34 + wd + 1]);
  }
}

// ---------------------------------------------------------------- per-iteration attention accumulation (bf16 k/v)
// grid: (8 chunks, 64 batches), 256 threads. Each block: 512 j's in 2 tiles of 256.
__global__ __launch_bounds__(256) void attn_acc(const uint16_t* __restrict__ kb, const uint16_t* __restrict__ vb,
                                                const float* __restrict__ qbuf,
                                                float* __restrict__ updbuf, float* __restrict__ rowsumbuf,
                                                float* __restrict__ aub, int lastIter){
  __shared__ float au[S_ * 257];       // [7][257] padded
  __shared__ float vtile[256 * 32];    // [256][32] f32, XOR-swizzled float4 blocks
  int b = blockIdx.y, chunk = blockIdx.x, t = threadIdx.x;

  int rem = t % 56, prt = t / 56;      // valid for t<224
  int pi = rem >> 3, pc4 = rem & 7;

  float rs[7];
  #pragma unroll
  for (int i = 0; i < 7; ++i) rs[i] = 0.f;
  float ux = 0.f, uy = 0.f, uz = 0.f, uw = 0.f;

  const float* qb = qbuf + b * (S_ * D_);           // wave-uniform -> s_load

  for (int tile = 0; tile < 2; ++tile){
    int j = chunk * 512 + tile * 256 + t;
    const uint4* kr = reinterpret_cast<const uint4*>(kb + ((size_t)b * N_ + j) * 32);
    float kf[32];
    #pragma unroll
    for (int p = 0; p < 4; ++p) up8(kr[p], kf + p * 8);

    float dv[7];
    #pragma unroll
    for (int i = 0; i < 7; ++i){
      const float* qr = qb + i * 32;
      float a = 0.f;
      #pragma unroll
      for (int c = 0; c < 32; ++c) a += qr[c] * kf[c];
      dv[i] = a * SCALE_;
    }
    float mx = dv[0];
    #pragma unroll
    for (int i = 1; i < 7; ++i) mx = fmaxf(mx, dv[i]);
    float p[7]; float sum = 0.f;
    #pragma unroll
    for (int i = 0; i < 7; ++i){ p[i] = __expf(dv[i] - mx); sum += p[i]; }
    float inv = 1.f / sum;
    #pragma unroll
    for (int i = 0; i < 7; ++i){
      p[i] = p[i] * inv + EPS_;
      rs[i] += p[i];
      au[i * 257 + t] = p[i];
    }
    if (lastIter){
      #pragma unroll
      for (int i = 0; i < 7; ++i) aub[(size_t)(b * S_ + i) * N_ + j] = p[i];
    }
    // stage v tile (f32, XOR-swizzled 16B blocks: logical block q4 stored at q4^(t&7))
    const uint4* vr = reinterpret_cast<const uint4*>(vb + ((size_t)b * N_ + j) * 32);
    float vf[32];
    #pragma unroll
    for (int p4 = 0; p4 < 4; ++p4) up8(vr[p4], vf + p4 * 8);
    #pragma unroll
    for (int q4 = 0; q4 < 8; ++q4){
      int blk = q4 ^ (t & 7);
      float4 vv = make_float4(vf[q4*4], vf[q4*4+1], vf[q4*4+2], vf[q4*4+3]);
      *reinterpret_cast<float4*>(&vtile[t * 32 + blk * 4]) = vv;
    }
    __syncthreads();

    if (t < 224){
      const float* aur = au + pi * 257 + prt * 64;
      #pragma unroll 4
      for (int jj0 = 0; jj0 < 64; ++jj0){
        int jj = prt * 64 + jj0;
        float a = aur[jj0];
        int blk = pc4 ^ (jj & 7);
        float4 vv = *reinterpret_cast<const float4*>(&vtile[jj * 32 + blk * 4]);
        ux += a * vv.x; uy += a * vv.y; uz += a * vv.z; uw += a * vv.w;
      }
    }
    __syncthreads();
  }

  // block-reduce rowsums (reuse au)
  #pragma unroll
  for (int i = 0; i < 7; ++i) au[i * 257 + t] = rs[i];
  __syncthreads();
  for (int off = 128; off >= 1; off >>= 1){
    if (t < off){
      #pragma unroll
      for (int i = 0; i < 7; ++i) au[i * 257 + t] += au[i * 257 + t + off];
    }
    __syncthreads();
  }
  if (t < 7) atomicAdd(&rowsumbuf[b * S_ + t], au[t * 257]);
  if (t < 224){
    float* up = updbuf + (size_t)(b * S_ + pi) * 32 + pc4 * 4;
    atomicAdd(up + 0, ux); atomicAdd(up + 1, uy);
    atomicAdd(up + 2, uz); atomicAdd(up + 3, uw);
  }
}

// ---------------------------------------------------------------- fused slot finalize (C) + next-iter prep (A)
__global__ __launch_bounds__(256) void slot_update(
    const float* __restrict__ slots_init,
    float* __restrict__ slotsbuf, float* __restrict__ updbuf, float* __restrict__ rowsumbuf,
    float* __restrict__ qbuf,
    const float* __restrict__ Wq,
    const float* __restrict__ lnsg, const float* __restrict__ lnsb,
    const float* __restrict__ gwi, const float* __restrict__ gwh,
    const float* __restrict__ gbi, const float* __restrict__ gbh,
    const float* __restrict__ lnmg, const float* __restrict__ lnmb,
    const float* __restrict__ w1, const float* __restrict__ b1,
    const float* __restrict__ w2, const float* __restrict__ b2,
    float* __restrict__ out0, float* __restrict__ out2,
    int doC, int doA, int isFinal)
{
  int b = blockIdx.x, t = threadIdx.x;
  int i = t >> 5, c = t & 31;
  __shared__ float sPrev[224], sU[224], sNew[224], sT[224], hM[896];
  float snew = 0.f;

  if (doC){
    if (t < 224){
      sPrev[t] = slotsbuf[b * 224 + t];
      sU[t] = updbuf[b * 224 + t] / rowsumbuf[b * S_ + i];
    }
    __syncthreads();
    if (t < 224){
      float gi[3], gh[3];
      #pragma unroll
      for (int x3 = 0; x3 < 3; ++x3){
        int gg = x3 * 32 + c;
        float ai = gbi[gg], ah = gbh[gg];
        #pragma unroll
        for (int d = 0; d < 32; ++d){
          ai += sU[i * 32 + d]    * gwi[gg * 32 + d];
          ah += sPrev[i * 32 + d] * gwh[gg * 32 + d];
        }
        gi[x3] = ai; gh[x3] = ah;
      }
      float r = 1.f / (1.f + __expf(-(gi[0] + gh[0])));
      float z = 1.f / (1.f + __expf(-(gi[1] + gh[1])));
      float n = tanhf(gi[2] + r * gh[2]);
      snew = (1.f - z) * n + z * sPrev[t];
      sNew[t] = snew;
    }
    __syncthreads();
    if (t < 224){                                       // LN_m
      float mu = 0.f, sq = 0.f;
      #pragma unroll
      for (int d = 0; d < 32; ++d){ float v = sNew[i * 32 + d]; mu += v; sq += v * v; }
      mu *= (1.f / 32.f);
      float var = sq * (1.f / 32.f) - mu * mu;
      float rstd = rsqrtf(var + LNEPS_);
      sT[t] = (snew - mu) * rstd * lnmg[c] + lnmb[c];
    }
    __syncthreads();
    if (t < 224){                                       // MLP layer 1 (4 cols/thread)
      #pragma unroll
      for (int kk = 0; kk < 4; ++kk){
        int hc = c + kk * 32;
        float a = b1[hc];
        #pragma unroll
        for (int d = 0; d < 32; ++d) a += sT[i * 32 + d] * w1[hc * 32 + d];
        hM[i * 128 + hc] = fmaxf(a, 0.f);
      }
    }
    __syncthreads();
    if (t < 224){                                       // MLP layer 2 + residual (4 indep accumulators)
      float a0 = 0.f, a1 = 0.f, a2 = 0.f, a3 = 0.f;
      for (int hh = 0; hh < 128; hh += 4){
        a0 += hM[i * 128 + hh    ] * w2[c * 128 + hh    ];
        a1 += hM[i * 128 + hh + 1] * w2[c * 128 + hh + 1];
        a2 += hM[i * 128 + hh + 2] * w2[c * 128 + hh + 2];
        a3 += hM[i * 128 + hh + 3] * w2[c * 128 + hh + 3];
      }
      snew = snew + b2[c] + ((a0 + a1) + (a2 + a3));
      slotsbuf[b * 224 + t] = snew;
      if (isFinal){ out0[b * 224 + t] = snew; out2[b * 224 + t] = snew; }
      sNew[t] = snew;
    }
  } else {
    if (t < 224){
      snew = slots_init[b * 224 + t];
      slotsbuf[b * 224 + t] = snew;
      sNew[t] = snew;
    }
  }

  if (doA){
    __syncthreads();
    if (t < 224){                                       // LN_s
      float mu = 0.f, sq = 0.f;
      #pragma unroll
      for (int d = 0; d < 32; ++d){ float v = sNew[i * 32 + d]; mu += v; sq += v * v; }
      mu *= (1.f / 32.f);
      float var = sq * (1.f / 32.f) - mu * mu;
      float rstd = rsqrtf(var + LNEPS_);
      sT[t] = (sNew[t] - mu) * rstd * lnsg[c] + lnsb[c];
    }
    __syncthreads();
    if (t < 224){                                       // q = s_ln @ Wq^T ; zero accumulators
      float a = 0.f;
      #pragma unroll
      for (int d = 0; d < 32; ++d) a += sT[i * 32 + d] * Wq[c * 32 + d];
      qbuf[b * 224 + t] = a;
      updbuf[b * 224 + t] = 0.f;
    }
    if (t < 7) rowsumbuf[b * S_ + t] = 0.f;
  }
}

// ---------------------------------------------------------------- final attn normalization -> f32 out
__global__ __launch_bounds__(256) void attn_final(const float* __restrict__ aub,
                                                  const float* __restrict__ rowsumbuf,
                                                  float* __restrict__ out1){
  int idx = blockIdx.x * 256 + threadIdx.x;   // < 64*7*4096
  int bi = idx >> 12;
  out1[idx] = aub[idx] / rowsumbuf[bi];
}

// ----------------------------------------------------------------
extern "C" void kernel_launch(void* const* d_in, const int* in_sizes, int n_in,
                              void* d_out, int out_size, void* d_ws, size_t ws_size,
                              hipStream_t stream)
{
  (void)in_sizes; (void)n_in; (void)out_size; (void)ws_size;
  const float* inp   = (const float*)d_in[0];
  const float* sini  = (const float*)d_in[1];
  const float* lng   = (const float*)d_in[2];
  const float* lnb   = (const float*)d_in[3];
  const float* Wk    = (const float*)d_in[4];
  const float* Wv    = (const float*)d_in[5];
  const float* Wq    = (const float*)d_in[6];
  const float* lnsg  = (const float*)d_in[7];
  const float* lnsb  = (const float*)d_in[8];
  const float* gwi   = (const float*)d_in[9];
  const float* gwh   = (const float*)d_in[10];
  const float* gbi   = (const float*)d_in[11];
  const float* gbh   = (const float*)d_in[12];
  const float* lnmg  = (const float*)d_in[13];
  const float* lnmb  = (const float*)d_in[14];
  const float* w1    = (const float*)d_in[15];
  const float* b1    = (const float*)d_in[16];
  const float* w2    = (const float*)d_in[17];
  const float* b2    = (const float*)d_in[18];

  char* w = (char*)d_ws;
  uint16_t* kbuf   = (uint16_t*)w; w += (size_t)B_ * N_ * 32 * 2;
  uint16_t* vbuf   = (uint16_t*)w; w += (size_t)B_ * N_ * 32 * 2;
  float* qbuf      = (float*)w; w += B_ * 224 * 4;
  float* slotsbuf  = (float*)w; w += B_ * 224 * 4;
  float* updbuf    = (float*)w; w += B_ * 224 * 4;
  float* rowsumbuf = (float*)w; w += B_ * S_ * 4;
  float* aubuf     = (float*)w; w += (size_t)B_ * S_ * N_ * 4;
  uint16_t* fragbuf= (uint16_t*)w; w += 8192 * 2;
  float* c1arr     = (float*)w; w += 64 * 4;
  float* c2arr     = (float*)w; w += 64 * 4;

  float* out0 = (float*)d_out;
  float* out1 = out0 + B_ * S_ * D_;
  float* out2 = out1 + B_ * S_ * N_;

  hipLaunchKernelGGL(init_w, dim3(5), dim3(256), 0, stream, Wk, Wv, lng, lnb, fragbuf, c1arr, c2arr);
  hipLaunchKernelGGL(ln_kv, dim3(4096), dim3(256), 0, stream, inp, fragbuf, c1arr, c2arr, kbuf, vbuf);

  // A0: slots <- slots_init, q0, zero accumulators
  hipLaunchKernelGGL(slot_update, dim3(64), dim3(256), 0, stream,
                     sini, slotsbuf, updbuf, rowsumbuf, qbuf, Wq, lnsg, lnsb,
                     gwi, gwh, gbi, gbh, lnmg, lnmb, w1, b1, w2, b2,
                     out0, out2, 0, 1, 0);

  for (int m = 0; m < 4; ++m){
    hipLaunchKernelGGL(attn_acc, dim3(8, 64), dim3(256), 0, stream,
                       kbuf, vbuf, qbuf, updbuf, rowsumbuf, aubuf, (m == 3) ? 1 : 0);
    hipLaunchKernelGGL(slot_update, dim3(64), dim3(256), 0, stream,
                       sini, slotsbuf, updbuf, rowsumbuf, qbuf, Wq, lnsg, lnsb,
                       gwi, gwh, gbi, gbh, lnmg, lnmb, w1, b1, w2, b2,
                       out0, out2, 1, (m < 3) ? 1 : 0, (m == 3) ? 1 : 0);
  }

  hipLaunchKernelGGL(attn_final, dim3((B_ * S_ * N_) / 256), dim3(256), 0, stream,
                     aubuf, rowsumbuf, out1);
}

// Round 12
// 184.606 us; speedup vs baseline: 1.3918x; 1.0091x over previous
//
#include <hip/hip_runtime.h>
#include <stdint.h>

#define B_   64
#define N_   4096
#define H_   128
#define S_   7
#define D_   32
#define SCALE_ 0.17677669529663687f   // 32^-0.5
#define EPS_   1e-8f
#define LNEPS_ 1e-5f
#define AUS_ 260                      // au row stride (multiple of 4 for b128 reads)

typedef __bf16 bf16x8 __attribute__((ext_vector_type(8)));
typedef float  floatx4 __attribute__((ext_vector_type(4)));

__device__ __forceinline__ uint32_t cvt2(float a, float b){
  union { __bf16 h[2]; uint32_t u; } r;
  r.h[0] = (__bf16)a; r.h[1] = (__bf16)b;
  return r.u;
}
__device__ __forceinline__ float bfLO(uint32_t u){ union{uint32_t i; float f;} x; x.i = u << 16;         return x.f; }
__device__ __forceinline__ float bfHI(uint32_t u){ union{uint32_t i; float f;} x; x.i = u & 0xffff0000u; return x.f; }
__device__ __forceinline__ void up8(uint4 u, float* o){
  o[0]=bfLO(u.x); o[1]=bfHI(u.x); o[2]=bfLO(u.y); o[3]=bfHI(u.y);
  o[4]=bfLO(u.z); o[5]=bfHI(u.z); o[6]=bfLO(u.w); o[7]=bfHI(u.w);
}

// ---------------------------------------------------------------- init: precompute W-fragments (g-folded, bf16) + c1/c2
__global__ __launch_bounds__(256) void init_w(const float* __restrict__ Wk, const float* __restrict__ Wv,
                                              const float* __restrict__ g,  const float* __restrict__ bta,
                                              uint16_t* __restrict__ fragbuf,
                                              float* __restrict__ c1arr, float* __restrict__ c2arr){
  int tid = blockIdx.x * 256 + threadIdx.x;
  if (blockIdx.x < 4){
    int nt = tid >> 8, kc = (tid >> 6) & 3, l = tid & 63;
    int col = (nt & 1) * 16 + (l & 15);
    int dbase = kc * 32 + (l >> 4) * 8;
    const float* wr = (nt < 2 ? Wk : Wv) + col * 128 + dbase;
    const float* gr = g + dbase;
    uint32_t u[4];
    #pragma unroll
    for (int j = 0; j < 4; ++j)
      u[j] = cvt2(wr[2*j] * gr[2*j], wr[2*j+1] * gr[2*j+1]);
    *reinterpret_cast<uint4*>(fragbuf + (size_t)tid * 8) = make_uint4(u[0], u[1], u[2], u[3]);
  } else {
    int t = threadIdx.x;
    if (t < 128){
      int which = t >> 5, col = t & 31;                 // 0:c1K 1:c2K 2:c1V 3:c2V
      const float* Wb  = (which & 2) ? Wv : Wk;
      const float* vec = (which & 1) ? bta : g;
      float a = 0.f;
      for (int d = 0; d < 128; ++d) a += vec[d] * Wb[col * 128 + d];
      float* dst = (which & 1) ? c2arr : c1arr;
      dst[(which >> 1) * 32 + col] = a;
    }
  }
}

// ---------------------------------------------------------------- LN(inputs) -> k,v via MFMA on raw x (LN folded into epilogue)
// 64 rows per block, 256 threads (4 waves). Grid 4096. k/v stored bf16.
__global__ __launch_bounds__(256) void ln_kv(const float* __restrict__ x,
                                             const uint16_t* __restrict__ fragbuf,
                                             const float* __restrict__ c1arr, const float* __restrict__ c2arr,
                                             uint16_t* __restrict__ kb, uint16_t* __restrict__ vb){
  __shared__ union {
    uint16_t atile[64 * 136];          // bf16 raw-x tile, row stride 136 (272B)
    float    rep[4352];                // repack area: k[64][34], v at +2176
  } sh;
  __shared__ float2 stats[32 * 65];    // [c][row] padded partial (s, s2)
  __shared__ float2 rowstat[64];       // (rstd, -mu*rstd)
  int t = threadIdx.x;
  int l = t & 63, w = t >> 6;
  size_t rowbase = (size_t)blockIdx.x * 64;

  // ---- B-frags: precomputed, coalesced dwordx4 loads
  bf16x8 bfr[4][4];                    // [nt][kc]
  #pragma unroll
  for (int nt = 0; nt < 4; ++nt)
    #pragma unroll
    for (int kc = 0; kc < 4; ++kc)
      bfr[nt][kc] = *reinterpret_cast<const bf16x8*>(fragbuf + (((nt * 4 + kc) * 64 + l) * 8));

  // ---- per-thread epilogue constants
  float c1c[4], c2c[4];
  #pragma unroll
  for (int nt = 0; nt < 4; ++nt){
    int colk = (nt & 1) * 16 + (l & 15);
    c1c[nt] = c1arr[(nt >> 1) * 32 + colk];
    c2c[nt] = c2arr[(nt >> 1) * 32 + colk];
  }

  // ---- pass1: load raw x, cast bf16 -> LDS, partial stats -> LDS
  const float4* xp = reinterpret_cast<const float4*>(x + rowbase * H_);
  #pragma unroll
  for (int k = 0; k < 8; ++k){
    float4 v = xp[k * 256 + t];        // coalesced 1KB per wave
    int row = 8 * k + (t >> 5);
    uint32_t lo = cvt2(v.x, v.y);
    uint32_t hi = cvt2(v.z, v.w);
    *reinterpret_cast<uint2*>(&sh.atile[row * 136 + (t & 31) * 4]) = make_uint2(lo, hi);
    float s  = v.x + v.y + v.z + v.w;
    float s2 = v.x*v.x + v.y*v.y + v.z*v.z + v.w*v.w;
    stats[(t & 31) * 65 + row] = make_float2(s, s2);
  }
  __syncthreads();

  // ---- shallow stats reduce: 8 independent LDS reads + 2 shfl levels
  {
    int row = t >> 2, q = t & 3;
    float s = 0.f, s2 = 0.f;
    #pragma unroll
    for (int j = 0; j < 8; ++j){
      float2 p = stats[(q * 8 + j) * 65 + row];
      s += p.x; s2 += p.y;
    }
    s  += __shfl_xor(s, 1);  s2 += __shfl_xor(s2, 1);
    s  += __shfl_xor(s, 2);  s2 += __shfl_xor(s2, 2);
    if (q == 0){
      float mean = s * (1.f / 128.f);
      float var  = s2 * (1.f / 128.f) - mean * mean;
      float rstd = rsqrtf(var + LNEPS_);
      rowstat[row] = make_float2(rstd, -mean * rstd);
    }
  }
  __syncthreads();

  // ---- MFMA: wave w -> rows w*16..w*16+15, all 64 out cols
  floatx4 acc[4] = {{0,0,0,0},{0,0,0,0},{0,0,0,0},{0,0,0,0}};
  #pragma unroll
  for (int kc = 0; kc < 4; ++kc){
    bf16x8 afr = *reinterpret_cast<const bf16x8*>(
        &sh.atile[(w * 16 + (l & 15)) * 136 + kc * 32 + (l >> 4) * 8]);
    #pragma unroll
    for (int nt = 0; nt < 4; ++nt)
      acc[nt] = __builtin_amdgcn_mfma_f32_16x16x32_bf16(afr, bfr[nt][kc], acc[nt], 0, 0, 0);
  }
  __syncthreads();                     // atile dead; rep aliases it

  // ---- epilogue: k = rstd*acc + (-mu*rstd)*c1 + c2 -> LDS repack area
  #pragma unroll
  for (int j = 0; j < 4; ++j){
    int rloc = w * 16 + (l >> 4) * 4 + j;
    float2 ab = rowstat[rloc];
    #pragma unroll
    for (int nt = 0; nt < 4; ++nt){
      int base = (nt < 2) ? 0 : 2176;
      int gc = (nt & 1) * 16 + (l & 15);
      sh.rep[base + rloc * 34 + gc] = fmaf(ab.x, acc[nt][j], fmaf(ab.y, c1c[nt], c2c[nt]));
    }
  }
  __syncthreads();

  // ---- pack bf16 pairs, coalesced uint32 stores
  uint32_t* kout = reinterpret_cast<uint32_t*>(kb + rowbase * 32);
  uint32_t* vout = reinterpret_cast<uint32_t*>(vb + rowbase * 32);
  #pragma unroll
  for (int it = 0; it < 4; ++it){
    int lin = it * 256 + t;
    int row = lin >> 4, wd = (lin & 15) * 2;
    kout[lin] = cvt2(sh.rep[row * 34 + wd],        sh.rep[row * 34 + wd + 1]);
    vout[lin] = cvt2(sh.rep[2176 + row * 34 + wd], sh.rep[2176 + row * 34 + wd + 1]);
  }
}

// ---------------------------------------------------------------- per-iteration attention accumulation (bf16 k/v)
// grid: (8 chunks, 64 batches), 256 threads. Each block: 512 j's in 2 tiles of 256.
__global__ __launch_bounds__(256) void attn_acc(const uint16_t* __restrict__ kb, const uint16_t* __restrict__ vb,
                                                const float* __restrict__ qbuf,
                                                float* __restrict__ updbuf, float* __restrict__ rowsumbuf,
                                                float* __restrict__ aub, int lastIter){
  __shared__ float au[S_ * AUS_];      // [7][260] (16B-aligned rows for b128 reads)
  __shared__ float vtile[256 * 32];    // [256][32] f32, XOR-swizzled float4 blocks
  int b = blockIdx.y, chunk = blockIdx.x, t = threadIdx.x;

  int rem = t % 56, prt = t / 56;      // valid for t<224
  int pi = rem >> 3, pc4 = rem & 7;

  float rs[7];
  #pragma unroll
  for (int i = 0; i < 7; ++i) rs[i] = 0.f;
  float ux = 0.f, uy = 0.f, uz = 0.f, uw = 0.f;

  const float* qb = qbuf + b * (S_ * D_);           // wave-uniform -> s_load

  for (int tile = 0; tile < 2; ++tile){
    int j = chunk * 512 + tile * 256 + t;
    const uint4* kr = reinterpret_cast<const uint4*>(kb + ((size_t)b * N_ + j) * 32);
    float kf[32];
    #pragma unroll
    for (int p = 0; p < 4; ++p) up8(kr[p], kf + p * 8);

    float dv[7];
    #pragma unroll
    for (int i = 0; i < 7; ++i){
      const float* qr = qb + i * 32;
      float a = 0.f;
      #pragma unroll
      for (int c = 0; c < 32; ++c) a += qr[c] * kf[c];
      dv[i] = a * SCALE_;
    }
    float mx = dv[0];
    #pragma unroll
    for (int i = 1; i < 7; ++i) mx = fmaxf(mx, dv[i]);
    float p[7]; float sum = 0.f;
    #pragma unroll
    for (int i = 0; i < 7; ++i){ p[i] = __expf(dv[i] - mx); sum += p[i]; }
    float inv = 1.f / sum;
    #pragma unroll
    for (int i = 0; i < 7; ++i){
      p[i] = p[i] * inv + EPS_;
      rs[i] += p[i];
      au[i * AUS_ + t] = p[i];
    }
    if (lastIter){
      #pragma unroll
      for (int i = 0; i < 7; ++i) aub[(size_t)(b * S_ + i) * N_ + j] = p[i];
    }
    // stage v tile (f32, XOR-swizzled 16B blocks: logical block q4 stored at q4^(t&7))
    const uint4* vr = reinterpret_cast<const uint4*>(vb + ((size_t)b * N_ + j) * 32);
    float vf[32];
    #pragma unroll
    for (int p4 = 0; p4 < 4; ++p4) up8(vr[p4], vf + p4 * 8);
    #pragma unroll
    for (int q4 = 0; q4 < 8; ++q4){
      int blk = q4 ^ (t & 7);
      float4 vv = make_float4(vf[q4*4], vf[q4*4+1], vf[q4*4+2], vf[q4*4+3]);
      *reinterpret_cast<float4*>(&vtile[t * 32 + blk * 4]) = vv;
    }
    __syncthreads();

    if (t < 224){
      const float* aur = au + pi * AUS_ + prt * 64;
      #pragma unroll 4
      for (int jj0 = 0; jj0 < 64; jj0 += 4){
        float4 a4 = *reinterpret_cast<const float4*>(&aur[jj0]);   // b128 au read
        int jj = prt * 64 + jj0;
        #pragma unroll
        for (int q = 0; q < 4; ++q){
          float a = (q == 0) ? a4.x : (q == 1) ? a4.y : (q == 2) ? a4.z : a4.w;
          int blk = pc4 ^ ((jj + q) & 7);
          float4 vv = *reinterpret_cast<const float4*>(&vtile[(jj + q) * 32 + blk * 4]);
          ux += a * vv.x; uy += a * vv.y; uz += a * vv.z; uw += a * vv.w;
        }
      }
    }
    __syncthreads();
  }

  // block-reduce rowsums (reuse au)
  #pragma unroll
  for (int i = 0; i < 7; ++i) au[i * AUS_ + t] = rs[i];
  __syncthreads();
  for (int off = 128; off >= 1; off >>= 1){
    if (t < off){
      #pragma unroll
      for (int i = 0; i < 7; ++i) au[i * AUS_ + t] += au[i * AUS_ + t + off];
    }
    __syncthreads();
  }
  if (t < 7) atomicAdd(&rowsumbuf[b * S_ + t], au[t * AUS_]);
  if (t < 224){
    float* up = updbuf + (size_t)(b * S_ + pi) * 32 + pc4 * 4;
    atomicAdd(up + 0, ux); atomicAdd(up + 1, uy);
    atomicAdd(up + 2, uz); atomicAdd(up + 3, uw);
  }
}

// ---------------------------------------------------------------- fused slot finalize (C) + next-iter prep (A)
__global__ __launch_bounds__(256) void slot_update(
    const float* __restrict__ slots_init,
    float* __restrict__ slotsbuf, float* __restrict__ updbuf, float* __restrict__ rowsumbuf,
    float* __restrict__ qbuf,
    const float* __restrict__ Wq,
    const float* __restrict__ lnsg, const float* __restrict__ lnsb,
    const float* __restrict__ gwi, const float* __restrict__ gwh,
    const float* __restrict__ gbi, const float* __restrict__ gbh,
    const float* __restrict__ lnmg, const float* __restrict__ lnmb,
    const float* __restrict__ w1, const float* __restrict__ b1,
    const float* __restrict__ w2, const float* __restrict__ b2,
    int doC, int doA)
{
  int b = blockIdx.x, t = threadIdx.x;
  int i = t >> 5, c = t & 31;
  __shared__ float sPrev[224], sU[224], sNew[224], sT[224], hM[896];
  float snew = 0.f;

  if (doC){
    if (t < 224){
      sPrev[t] = slotsbuf[b * 224 + t];
      sU[t] = updbuf[b * 224 + t] / rowsumbuf[b * S_ + i];
    }
    __syncthreads();
    if (t < 224){
      float gi[3], gh[3];
      #pragma unroll
      for (int x3 = 0; x3 < 3; ++x3){
        int gg = x3 * 32 + c;
        float ai = gbi[gg], ah = gbh[gg];
        #pragma unroll
        for (int d = 0; d < 32; ++d){
          ai += sU[i * 32 + d]    * gwi[gg * 32 + d];
          ah += sPrev[i * 32 + d] * gwh[gg * 32 + d];
        }
        gi[x3] = ai; gh[x3] = ah;
      }
      float r = 1.f / (1.f + __expf(-(gi[0] + gh[0])));
      float z = 1.f / (1.f + __expf(-(gi[1] + gh[1])));
      float n = tanhf(gi[2] + r * gh[2]);
      snew = (1.f - z) * n + z * sPrev[t];
      sNew[t] = snew;
    }
    __syncthreads();
    if (t < 224){                                       // LN_m
      float mu = 0.f, sq = 0.f;
      #pragma unroll
      for (int d = 0; d < 32; ++d){ float v = sNew[i * 32 + d]; mu += v; sq += v * v; }
      mu *= (1.f / 32.f);
      float var = sq * (1.f / 32.f) - mu * mu;
      float rstd = rsqrtf(var + LNEPS_);
      sT[t] = (snew - mu) * rstd * lnmg[c] + lnmb[c];
    }
    __syncthreads();
    if (t < 224){                                       // MLP layer 1 (4 cols/thread)
      #pragma unroll
      for (int kk = 0; kk < 4; ++kk){
        int hc = c + kk * 32;
        float a = b1[hc];
        #pragma unroll
        for (int d = 0; d < 32; ++d) a += sT[i * 32 + d] * w1[hc * 32 + d];
        hM[i * 128 + hc] = fmaxf(a, 0.f);
      }
    }
    __syncthreads();
    if (t < 224){                                       // MLP layer 2 + residual (4 indep accumulators)
      float a0 = 0.f, a1 = 0.f, a2 = 0.f, a3 = 0.f;
      for (int hh = 0; hh < 128; hh += 4){
        a0 += hM[i * 128 + hh    ] * w2[c * 128 + hh    ];
        a1 += hM[i * 128 + hh + 1] * w2[c * 128 + hh + 1];
        a2 += hM[i * 128 + hh + 2] * w2[c * 128 + hh + 2];
        a3 += hM[i * 128 + hh + 3] * w2[c * 128 + hh + 3];
      }
      snew = snew + b2[c] + ((a0 + a1) + (a2 + a3));
      slotsbuf[b * 224 + t] = snew;
      sNew[t] = snew;
    }
  } else {
    if (t < 224){
      snew = slots_init[b * 224 + t];
      slotsbuf[b * 224 + t] = snew;
      sNew[t] = snew;
    }
  }

  if (doA){
    __syncthreads();
    if (t < 224){                                       // LN_s
      float mu = 0.f, sq = 0.f;
      #pragma unroll
      for (int d = 0; d < 32; ++d){ float v = sNew[i * 32 + d]; mu += v; sq += v * v; }
      mu *= (1.f / 32.f);
      float var = sq * (1.f / 32.f) - mu * mu;
      float rstd = rsqrtf(var + LNEPS_);
      sT[t] = (sNew[t] - mu) * rstd * lnsg[c] + lnsb[c];
    }
    __syncthreads();
    if (t < 224){                                       // q = s_ln @ Wq^T ; zero accumulators
      float a = 0.f;
      #pragma unroll
      for (int d = 0; d < 32; ++d) a += sT[i * 32 + d] * Wq[c * 32 + d];
      qbuf[b * 224 + t] = a;
      updbuf[b * 224 + t] = 0.f;
    }
    if (t < 7) rowsumbuf[b * S_ + t] = 0.f;
  }
}

// ---------------------------------------------------------------- finalize: blocks 0-63 final slot update -> out0/out2; blocks 64-511 normalize -> out1
__global__ __launch_bounds__(256) void finalize(
    const float* __restrict__ slotsbuf, const float* __restrict__ updbuf,
    const float* __restrict__ rowsumbuf, const float* __restrict__ aubuf,
    const float* __restrict__ gwi, const float* __restrict__ gwh,
    const float* __restrict__ gbi, const float* __restrict__ gbh,
    const float* __restrict__ lnmg, const float* __restrict__ lnmb,
    const float* __restrict__ w1, const float* __restrict__ b1,
    const float* __restrict__ w2, const float* __restrict__ b2,
    float* __restrict__ out0, float* __restrict__ out1, float* __restrict__ out2)
{
  int t = threadIdx.x;
  if (blockIdx.x >= 64){
    int blk = blockIdx.x - 64;                          // 0..447
    #pragma unroll
    for (int k2 = 0; k2 < 4; ++k2){
      int idx4 = blk * 1024 + k2 * 256 + t;             // < 458752
      int bi = idx4 >> 10;                              // (b*7+i)
      float inv = 1.f / rowsumbuf[bi];
      float4 a = reinterpret_cast<const float4*>(aubuf)[idx4];
      reinterpret_cast<float4*>(out1)[idx4] = make_float4(a.x*inv, a.y*inv, a.z*inv, a.w*inv);
    }
    return;
  }
  int b = blockIdx.x;
  int i7 = t >> 5, c = t & 31;
  __shared__ float sPrev[224], sU[224], sNew[224], sT[224], hM[896];
  float snew = 0.f;
  if (t < 224){
    sPrev[t] = slotsbuf[b * 224 + t];
    sU[t] = updbuf[b * 224 + t] / rowsumbuf[b * S_ + i7];
  }
  __syncthreads();
  if (t < 224){                                         // GRU
    float gi[3], gh[3];
    #pragma unroll
    for (int x3 = 0; x3 < 3; ++x3){
      int gg = x3 * 32 + c;
      float ai = gbi[gg], ah = gbh[gg];
      #pragma unroll
      for (int d = 0; d < 32; ++d){
        ai += sU[i7 * 32 + d]    * gwi[gg * 32 + d];
        ah += sPrev[i7 * 32 + d] * gwh[gg * 32 + d];
      }
      gi[x3] = ai; gh[x3] = ah;
    }
    float r = 1.f / (1.f + __expf(-(gi[0] + gh[0])));
    float z = 1.f / (1.f + __expf(-(gi[1] + gh[1])));
    float n = tanhf(gi[2] + r * gh[2]);
    snew = (1.f - z) * n + z * sPrev[t];
    sNew[t] = snew;
  }
  __syncthreads();
  if (t < 224){                                         // LN_m
    float mu = 0.f, sq = 0.f;
    #pragma unroll
    for (int d = 0; d < 32; ++d){ float v = sNew[i7 * 32 + d]; mu += v; sq += v * v; }
    mu *= (1.f / 32.f);
    float var = sq * (1.f / 32.f) - mu * mu;
    float rstd = rsqrtf(var + LNEPS_);
    sT[t] = (snew - mu) * rstd * lnmg[c] + lnmb[c];
  }
  __syncthreads();
  if (t < 224){                                         // MLP layer 1
    #pragma unroll
    for (int kk = 0; kk < 4; ++kk){
      int hc = c + kk * 32;
      float a = b1[hc];
      #pragma unroll
      for (int d = 0; d < 32; ++d) a += sT[i7 * 32 + d] * w1[hc * 32 + d];
      hM[i7 * 128 + hc] = fmaxf(a, 0.f);
    }
  }
  __syncthreads();
  if (t < 224){                                         // MLP layer 2 + residual -> final slots
    float a0 = 0.f, a1 = 0.f, a2 = 0.f, a3 = 0.f;
    for (int hh = 0; hh < 128; hh += 4){
      a0 += hM[i7 * 128 + hh    ] * w2[c * 128 + hh    ];
      a1 += hM[i7 * 128 + hh + 1] * w2[c * 128 + hh + 1];
      a2 += hM[i7 * 128 + hh + 2] * w2[c * 128 + hh + 2];
      a3 += hM[i7 * 128 + hh + 3] * w2[c * 128 + hh + 3];
    }
    snew = snew + b2[c] + ((a0 + a1) + (a2 + a3));
    out0[b * 224 + t] = snew;
    out2[b * 224 + t] = snew;
  }
}

// ----------------------------------------------------------------
extern "C" void kernel_launch(void* const* d_in, const int* in_sizes, int n_in,
                              void* d_out, int out_size, void* d_ws, size_t ws_size,
                              hipStream_t stream)
{
  (void)in_sizes; (void)n_in; (void)out_size; (void)ws_size;
  const float* inp   = (const float*)d_in[0];
  const float* sini  = (const float*)d_in[1];
  const float* lng   = (const float*)d_in[2];
  const float* lnb   = (const float*)d_in[3];
  const float* Wk    = (const float*)d_in[4];
  const float* Wv    = (const float*)d_in[5];
  const float* Wq    = (const float*)d_in[6];
  const float* lnsg  = (const float*)d_in[7];
  const float* lnsb  = (const float*)d_in[8];
  const float* gwi   = (const float*)d_in[9];
  const float* gwh   = (const float*)d_in[10];
  const float* gbi   = (const float*)d_in[11];
  const float* gbh   = (const float*)d_in[12];
  const float* lnmg  = (const float*)d_in[13];
  const float* lnmb  = (const float*)d_in[14];
  const float* w1    = (const float*)d_in[15];
  const float* b1    = (const float*)d_in[16];
  const float* w2    = (const float*)d_in[17];
  const float* b2    = (const float*)d_in[18];

  char* w = (char*)d_ws;
  uint16_t* kbuf   = (uint16_t*)w; w += (size_t)B_ * N_ * 32 * 2;
  uint16_t* vbuf   = (uint16_t*)w; w += (size_t)B_ * N_ * 32 * 2;
  float* qbuf      = (float*)w; w += B_ * 224 * 4;
  float* slotsbuf  = (float*)w; w += B_ * 224 * 4;
  float* updbuf    = (float*)w; w += B_ * 224 * 4;
  float* rowsumbuf = (float*)w; w += B_ * S_ * 4;
  float* aubuf     = (float*)w; w += (size_t)B_ * S_ * N_ * 4;
  uint16_t* fragbuf= (uint16_t*)w; w += 8192 * 2;
  float* c1arr     = (float*)w; w += 64 * 4;
  float* c2arr     = (float*)w; w += 64 * 4;

  float* out0 = (float*)d_out;
  float* out1 = out0 + B_ * S_ * D_;
  float* out2 = out1 + B_ * S_ * N_;

  hipLaunchKernelGGL(init_w, dim3(5), dim3(256), 0, stream, Wk, Wv, lng, lnb, fragbuf, c1arr, c2arr);
  hipLaunchKernelGGL(ln_kv, dim3(4096), dim3(256), 0, stream, inp, fragbuf, c1arr, c2arr, kbuf, vbuf);

  // A0: slots <- slots_init, q0, zero accumulators
  hipLaunchKernelGGL(slot_update, dim3(64), dim3(256), 0, stream,
                     sini, slotsbuf, updbuf, rowsumbuf, qbuf, Wq, lnsg, lnsb,
                     gwi, gwh, gbi, gbh, lnmg, lnmb, w1, b1, w2, b2,
                     0, 1);

  for (int m = 0; m < 4; ++m){
    hipLaunchKernelGGL(attn_acc, dim3(8, 64), dim3(256), 0, stream,
                       kbuf, vbuf, qbuf, updbuf, rowsumbuf, aubuf, (m == 3) ? 1 : 0);
    if (m < 3){
      hipLaunchKernelGGL(slot_update, dim3(64), dim3(256), 0, stream,
                         sini, slotsbuf, updbuf, rowsumbuf, qbuf, Wq, lnsg, lnsb,
                         gwi, gwh, gbi, gbh, lnmg, lnmb, w1, b1, w2, b2,
                         1, 1);
    }
  }

  hipLaunchKernelGGL(finalize, dim3(512), dim3(256), 0, stream,
                     slotsbuf, updbuf, rowsumbuf, aubuf,
                     gwi, gwh, gbi, gbh, lnmg, lnmb, w1, b1, w2, b2,
                     out0, out1, out2);
}